// Round 14
// baseline (469.357 us; speedup 1.0000x reference)
//
#include <hip/hip_runtime.h>
#include <hip/hip_bf16.h>

typedef __attribute__((ext_vector_type(4))) float f32x4;
typedef __attribute__((ext_vector_type(8))) short short8;
typedef __attribute__((ext_vector_type(4))) unsigned int u32x4;

__device__ __forceinline__ unsigned short f2bf(float f) {
  union { float f; unsigned int u; } v; v.f = f;
  unsigned int r = (v.u + 0x7fffu + ((v.u >> 16) & 1u)) >> 16;
  return (unsigned short)r;
}
__device__ __forceinline__ unsigned short f2bf_fast(float f) {
  __hip_bfloat16 h = __float2bfloat16(f);
  return __builtin_bit_cast(unsigned short, h);
}
__device__ __forceinline__ float bf2f(unsigned short h) {
  union { unsigned int u; float f; } v; v.u = ((unsigned int)h) << 16;
  return v.f;
}
__device__ __forceinline__ unsigned int cvt_pk_bf16(float lo, float hi) {
  unsigned int r;
  asm("v_cvt_pk_bf16_f32 %0, %1, %2" : "=v"(r) : "v"(lo), "v"(hi));
  return r;
}

__device__ __forceinline__ void gload_lds16(const void* g, void* l) {
  __builtin_amdgcn_global_load_lds((const __attribute__((address_space(1))) void*)g,
                                   (__attribute__((address_space(3))) void*)l,
                                   16, 0, 0);
}

template <int N>
__device__ __forceinline__ void vmwait() {
  asm volatile("s_waitcnt vmcnt(%0)" :: "n"(N) : "memory");
}
__device__ __forceinline__ void lgkm0() {
  asm volatile("s_waitcnt lgkmcnt(0)" ::: "memory");
}

// ---------------- f32 -> bf16 convert (hidden states only) ----------------
__global__ __launch_bounds__(256) void cvt_hid(const float* __restrict__ in,
                                               unsigned short* __restrict__ out,
                                               int n) {
  size_t stride = (size_t)gridDim.x * blockDim.x;
  for (size_t i = (size_t)blockIdx.x * blockDim.x + threadIdx.x; i * 4 < (size_t)n; i += stride) {
    float4 v = *(const float4*)(in + i * 4);
    ushort4 o;
    o.x = f2bf(v.x); o.y = f2bf(v.y); o.z = f2bf(v.z); o.w = f2bf(v.w);
    *(ushort4*)(out + i * 4) = o;
  }
}

// ---------------- BK=64 double-buffered GEMM, f32 B with fused convert ----------------
// Round-14 fix vs round-13: B-global prefetch is 2 iterations deep (two NAMED
// reg sets brA/brB, 2x-unrolled loop -> static indexing), so the end-of-iter
// wait vmcnt(ALOADS+2*BLOADS) only requires B(t+1) (issued a FULL iteration
// earlier, ~1500cy > 900cy HBM) -- never drains the just-issued loads.
// In-order vmcnt retirement proofs:
//   top wait vmcnt(2*BLOADS): newest 2*BLOADS = B(t+1) loads -> A(t) landed.
//   end wait vmcnt(ALOADS+2*BLOADS): newest = A(t+1)+B(t+2) -> B(t+1) landed.
#define LOADB(T, BR)                                                          \
  {                                                                           \
    const int k0 = (T) * BK;                                                  \
    _Pragma("unroll") for (int i = 0; i < BLOADS; ++i) {                      \
      int grow = col0 + i * 32;                                               \
      const float* src; int rrow;                                             \
      if (grow < b1)      { src = B0; rrow = grow; }                          \
      else if (grow < b2) { src = B1; rrow = grow - b1; }                     \
      else                { src = B2; rrow = grow - b2; }                     \
      const float* p = src + (size_t)(rrow + srow) * K + k0 + spsw * 8;       \
      BR[2 * i]     = *(const float4*)p;                                      \
      BR[2 * i + 1] = *(const float4*)(p + 4);                                \
    }                                                                         \
  }
#define WRITEB(T, BR)                                                         \
  {                                                                           \
    unsigned short* buf = &lds[((T) & 1) * BUF];                              \
    _Pragma("unroll") for (int i = 0; i < BLOADS; ++i) {                      \
      u32x4 w;                                                                \
      w[0] = cvt_pk_bf16(BR[2 * i].x, BR[2 * i].y);                           \
      w[1] = cvt_pk_bf16(BR[2 * i].z, BR[2 * i].w);                           \
      w[2] = cvt_pk_bf16(BR[2 * i + 1].x, BR[2 * i + 1].y);                   \
      w[3] = cvt_pk_bf16(BR[2 * i + 1].z, BR[2 * i + 1].w);                   \
      *(u32x4*)&buf[ASH + i * 2048 + tid * 8] = w;                            \
    }                                                                         \
  }

template <int BM, int BN, bool BF16_OUT>
__global__ __launch_bounds__(256, 2) void gemm_f32b(
    const unsigned short* __restrict__ A,
    const float* __restrict__ B0, const float* __restrict__ B1,
    const float* __restrict__ B2, int b1, int b2,
    void* __restrict__ Cout, int M, int N, int K) {
  constexpr int BK = 64;
  constexpr int MFRAG = BM / 32;
  constexpr int NFRAG = BN / 32;
  constexpr int ASH = BM * BK;
  constexpr int BSH = BN * BK;
  constexpr int BUF = ASH + BSH;
  constexpr int ALOADS = BM / 32;
  constexpr int BLOADS = BN / 32;
  constexpr int NB = 2 * BLOADS;          // B load instructions per tile
  constexpr int TOPW = NB;                // top-of-iter wait
  constexpr int ENDW = ALOADS + NB;       // end-of-iter wait
  __shared__ unsigned short lds[2 * BUF];

  const int tid = threadIdx.x;
  const int wave = tid >> 6, lane = tid & 63;
  const int l15 = lane & 15, l4 = lane >> 4;
  const int row0 = blockIdx.y * BM, col0 = blockIdx.x * BN;
  const int mrow0 = (wave >> 1) * (BM / 2);
  const int ncol0 = (wave & 1) * (BN / 2);
  const int NT = K >> 6;                  // 64 for K=4096 (even, >= 4)
  const int srow = tid >> 3;
  const int spsw = (tid & 7) ^ (srow & 7);

  f32x4 zv = {0.f, 0.f, 0.f, 0.f};
  f32x4 acc[MFRAG][NFRAG];
#pragma unroll
  for (int m = 0; m < MFRAG; ++m)
#pragma unroll
    for (int n = 0; n < NFRAG; ++n) acc[m][n] = zv;

  float4 brA[NB], brB[NB];

  auto stageA = [&](int t) {
    unsigned short* buf = &lds[(t & 1) * BUF];
    const int k0 = t * BK;
#pragma unroll
    for (int i = 0; i < ALOADS; ++i)
      gload_lds16(A + (size_t)(row0 + i * 32 + srow) * K + k0 + spsw * 8,
                  buf + i * 2048 + tid * 8);
  };
  auto compute = [&](int t) {
    const unsigned short* Ab = &lds[(t & 1) * BUF];
    const unsigned short* Bb = Ab + ASH;
#pragma unroll
    for (int h = 0; h < 2; ++h) {
      short8 afr[MFRAG], bfr[NFRAG];
#pragma unroll
      for (int m = 0; m < MFRAG; ++m) {
        int row = mrow0 + m * 16 + l15;
        afr[m] = *(const short8*)&Ab[row * 64 + (((h * 4 + l4) ^ (l15 & 7)) * 8)];
      }
#pragma unroll
      for (int n = 0; n < NFRAG; ++n) {
        int row = ncol0 + n * 16 + l15;
        bfr[n] = *(const short8*)&Bb[row * 64 + (((h * 4 + l4) ^ (l15 & 7)) * 8)];
      }
      __builtin_amdgcn_s_setprio(1);
#pragma unroll
      for (int m = 0; m < MFRAG; ++m)
#pragma unroll
        for (int n = 0; n < NFRAG; ++n)
          acc[m][n] = __builtin_amdgcn_mfma_f32_16x16x32_bf16(afr[m], bfr[n], acc[m][n], 0, 0, 0);
      __builtin_amdgcn_s_setprio(0);
    }
  };

  // prologue: B(0) -> LDS, B(1) -> brB, A(0) staged
  LOADB(0, brA);
  vmwait<0>();
  WRITEB(0, brA);
  stageA(0);
  LOADB(1, brB);

  for (int t = 0; t < NT - 2; t += 2) {
    // ---- even iter t: load B(t+2)->brA, write B(t+1) from brB ----
    vmwait<TOPW>();
    lgkm0();
    __builtin_amdgcn_sched_barrier(0);
    __builtin_amdgcn_s_barrier();
    __builtin_amdgcn_sched_barrier(0);
    stageA(t + 1);
    LOADB(t + 2, brA);
    compute(t);
    vmwait<ENDW>();
    __builtin_amdgcn_sched_barrier(0);
    WRITEB(t + 1, brB);
    // ---- odd iter t+1: load B(t+3)->brB, write B(t+2) from brA ----
    vmwait<TOPW>();
    lgkm0();
    __builtin_amdgcn_sched_barrier(0);
    __builtin_amdgcn_s_barrier();
    __builtin_amdgcn_sched_barrier(0);
    stageA(t + 2);
    LOADB(t + 3, brB);
    compute(t + 1);
    vmwait<ENDW>();
    __builtin_amdgcn_sched_barrier(0);
    WRITEB(t + 2, brA);
  }

  // peel iter NT-2 (even parity): brB holds B(NT-1)
  vmwait<0>();
  lgkm0();
  __builtin_amdgcn_sched_barrier(0);
  __builtin_amdgcn_s_barrier();
  __builtin_amdgcn_sched_barrier(0);
  stageA(NT - 1);
  compute(NT - 2);
  WRITEB(NT - 1, brB);
  // peel iter NT-1
  vmwait<0>();
  lgkm0();
  __builtin_amdgcn_sched_barrier(0);
  __builtin_amdgcn_s_barrier();
  __builtin_amdgcn_sched_barrier(0);
  compute(NT - 1);

#pragma unroll
  for (int m = 0; m < MFRAG; ++m)
#pragma unroll
    for (int n = 0; n < NFRAG; ++n)
#pragma unroll
      for (int j = 0; j < 4; ++j) {
        int r = row0 + mrow0 + m * 16 + l4 * 4 + j;
        int cc = col0 + ncol0 + n * 16 + l15;
        if constexpr (BF16_OUT)
          ((unsigned short*)Cout)[(size_t)r * N + cc] = f2bf(acc[m][n][j]);
        else
          ((float*)Cout)[(size_t)r * N + cc] = acc[m][n][j];
      }
}

// ---------------- RoPE (in-place on fused QKV [2048][6144]) ----------------
__global__ __launch_bounds__(256) void rope_k(unsigned short* __restrict__ QKV) {
  int idx = blockIdx.x * blockDim.x + threadIdx.x;
  if (idx >= 2048 * 40 * 64) return;
  int j = idx & 63;
  int rest = idx >> 6;
  int slot = rest % 40;
  int s = rest / 40;
  int doff = (slot < 32) ? slot * 128 : 4096 + (slot - 32) * 128;
  unsigned short* p = QKV + (size_t)s * 6144 + doff;
  float inv = exp2f((float)j * -0.20762050593046015f);
  float ang = (float)s * inv;
  float sn, cs;
  sincosf(ang, &sn, &cs);
  float x1 = bf2f(p[j]), x2 = bf2f(p[j + 64]);
  p[j]      = f2bf(x1 * cs - x2 * sn);
  p[j + 64] = f2bf(x2 * cs + x1 * sn);
}

// ---------------- causal GQA flash attention (round-11 verbatim: 106us, VGPR 64) ----------------
__global__ __launch_bounds__(512, 4) void attn_k(
    const unsigned short* __restrict__ QKV,  // [2048][6144]
    unsigned short* __restrict__ O) {        // [2048][4096]
  __shared__ unsigned short Ks[2][64 * 128];
  __shared__ unsigned short Vs[2][64 * 128];

  const int tid = threadIdx.x;
  const int wave = tid >> 6, lane = tid & 63;
  const int l15 = lane & 15, l4 = lane >> 4;

  const int bid = blockIdx.x;
  const int qt16 = bid & 15;
  const int h = (bid >> 4) & 31;
  const int qt = (h < 16) ? (15 - qt16) : qt16;
  const int hkv = h >> 2;
  const int q0 = qt * 128;
  const int qrow = q0 + wave * 16 + l15;
  const float C2 = 0.12751744219938793f;  // log2(e)/sqrt(128)

  const unsigned short* Qp = QKV + h * 128;
  const unsigned short* Kp = QKV + 4096 + hkv * 128;
  const unsigned short* Vp = QKV + 5120 + hkv * 128;

  const int vpr = tid >> 4;
  const int vd8 = tid & 15;
  const int vg8 = vpr >> 2, vjj = 2 * (vpr & 3);
  const int vn = vd8 >> 1, vch = (vd8 & 1) * 8;

  short8 qf[4];
#pragma unroll
  for (int kc = 0; kc < 4; ++kc)
    qf[kc] = *(const short8*)(Qp + (size_t)qrow * 6144 + kc * 32 + l4 * 8);

  f32x4 zv = {0.f, 0.f, 0.f, 0.f};
  f32x4 oacc[8];
#pragma unroll
  for (int n = 0; n < 8; ++n) oacc[n] = zv;
  float mrow = -3.0e38f, lrow = 0.f;

  auto stageK = [&](int kvn, int b) {
#pragma unroll
    for (int i = 0; i < 2; ++i) {
      int c = wave * 2 + i;
      int row = c * 4 + l4;
      int colel = (l15 * 8) ^ ((row & 7) << 3);
      gload_lds16(Kp + (size_t)(kvn + row) * 6144 + colel, &Ks[b][c * 512]);
    }
  };
  auto loadV = [&](int kvn, short8& va, short8& vb) {
    va = *(const short8*)(Vp + (size_t)(kvn + 2 * vpr) * 6144 + vd8 * 8);
    vb = *(const short8*)(Vp + (size_t)(kvn + 2 * vpr + 1) * 6144 + vd8 * 8);
  };
  auto writeV = [&](int b, const short8& va, const short8& vb) {
#pragma unroll
    for (int i = 0; i < 8; ++i) {
      int c = vch + i;
      unsigned int pack = (unsigned int)(unsigned short)va[i] |
                          ((unsigned int)(unsigned short)vb[i] << 16);
      *(unsigned int*)&Vs[b][vg8 * 1024 + vn * 128 + ((c ^ vn) & 15) * 8 + vjj] = pack;
    }
  };

  {
    short8 va, vb;
    stageK(0, 0);
    loadV(0, va, vb);
    writeV(0, va, vb);
  }
  __syncthreads();

  const int nt = 2 * qt + 2;
  for (int t = 0; t < nt; ++t) {
    const int cur = t & 1, nxt = cur ^ 1;
    const int kv0 = t * 64;
    const bool has_next = (t + 1 < nt);
    short8 va, vb;
    if (has_next) {
      stageK(kv0 + 64, nxt);
      loadV(kv0 + 64, va, vb);
    }

    f32x4 sacc[4];
#pragma unroll
    for (int cb = 0; cb < 4; ++cb) sacc[cb] = zv;
    __builtin_amdgcn_s_setprio(1);
#pragma unroll
    for (int cb = 0; cb < 4; ++cb) {
      int row = cb * 16 + l15;
      int sw = (row & 7) << 3;
#pragma unroll
      for (int kc = 0; kc < 4; ++kc) {
        short8 kf = *(const short8*)&Ks[cur][row * 128 + ((kc * 32 + l4 * 8) ^ sw)];
        sacc[cb] = __builtin_amdgcn_mfma_f32_16x16x32_bf16(kf, qf[kc], sacc[cb], 0, 0, 0);
      }
    }
    __builtin_amdgcn_s_setprio(0);

    if (kv0 + 63 > q0 + wave * 16) {
#pragma unroll
      for (int cb = 0; cb < 4; ++cb)
#pragma unroll
        for (int j = 0; j < 4; ++j) {
          int kvpos = kv0 + cb * 16 + l4 * 4 + j;
          if (kvpos > qrow) sacc[cb][j] = -3.0e38f;
        }
    }

    float pm = sacc[0][0];
#pragma unroll
    for (int cb = 0; cb < 4; ++cb)
#pragma unroll
      for (int j = 0; j < 4; ++j) pm = fmaxf(pm, sacc[cb][j]);
    pm = fmaxf(pm, __shfl_xor(pm, 16, 64));
    pm = fmaxf(pm, __shfl_xor(pm, 32, 64));

    if (__any(pm > mrow + 64.0f)) {
      float mn = fmaxf(mrow, pm);
      float rs = exp2f((mrow - mn) * C2);
      mrow = mn;
      lrow *= rs;
      float rs0 = __shfl(rs, 4 * l4 + 0, 64);
      float rs1 = __shfl(rs, 4 * l4 + 1, 64);
      float rs2 = __shfl(rs, 4 * l4 + 2, 64);
      float rs3 = __shfl(rs, 4 * l4 + 3, 64);
#pragma unroll
      for (int n = 0; n < 8; ++n) {
        oacc[n][0] *= rs0; oacc[n][1] *= rs1;
        oacc[n][2] *= rs2; oacc[n][3] *= rs3;
      }
    }

    unsigned int pack[8];
    float psum = 0.f;
#pragma unroll
    for (int cb = 0; cb < 4; ++cb) {
      float p0 = exp2f((sacc[cb][0] - mrow) * C2);
      float p1 = exp2f((sacc[cb][1] - mrow) * C2);
      float p2 = exp2f((sacc[cb][2] - mrow) * C2);
      float p3 = exp2f((sacc[cb][3] - mrow) * C2);
      psum += (p0 + p1) + (p2 + p3);
      pack[cb * 2 + 0] = cvt_pk_bf16(p0, p1);
      pack[cb * 2 + 1] = cvt_pk_bf16(p2, p3);
    }
    lrow += psum;

#pragma unroll
    for (int ks = 0; ks < 2; ++ks) {
      u32x4 pw;
#pragma unroll
      for (int w = 0; w < 4; ++w) {
        int sl = l15 + 16 * ((2 * l4 + (w >> 1)) & 3);
        int v0 = __shfl((int)pack[4 * ks + (w & 1)], sl, 64);
        int v1 = __shfl((int)pack[4 * ks + 2 + (w & 1)], sl, 64);
        pw[w] = (lane < 32) ? (unsigned int)v0 : (unsigned int)v1;
      }
      short8 pf = __builtin_bit_cast(short8, pw);
      __builtin_amdgcn_s_setprio(1);
#pragma unroll
      for (int n = 0; n < 8; ++n) {
        short8 vf = *(const short8*)&Vs[cur][(ks * 4 + l4) * 1024 + n * 128 + ((l15 ^ n) & 15) * 8];
        oacc[n] = __builtin_amdgcn_mfma_f32_16x16x32_bf16(pf, vf, oacc[n], 0, 0, 0);
      }
      __builtin_amdgcn_s_setprio(0);
    }

    if (has_next) writeV(nxt, va, vb);
    __syncthreads();
  }

  lrow += __shfl_xor(lrow, 16, 64);
  lrow += __shfl_xor(lrow, 32, 64);
  float linv = 1.0f / lrow;
  float li0 = __shfl(linv, 4 * l4 + 0, 64);
  float li1 = __shfl(linv, 4 * l4 + 1, 64);
  float li2 = __shfl(linv, 4 * l4 + 2, 64);
  float li3 = __shfl(linv, 4 * l4 + 3, 64);
#pragma unroll
  for (int n = 0; n < 8; ++n) {
    int r = q0 + wave * 16 + l4 * 4;
    size_t base = (size_t)r * 4096 + h * 128 + n * 16 + l15;
    O[base]          = f2bf_fast(oacc[n][0] * li0);
    O[base + 4096]   = f2bf_fast(oacc[n][1] * li1);
    O[base + 8192]   = f2bf_fast(oacc[n][2] * li2);
    O[base + 12288]  = f2bf_fast(oacc[n][3] * li3);
  }
}

extern "C" void kernel_launch(void* const* d_in, const int* in_sizes, int n_in,
                              void* d_out, int out_size, void* d_ws, size_t ws_size,
                              hipStream_t stream) {
  const float* hid = (const float*)d_in[0];
  const float* Wq  = (const float*)d_in[1];
  const float* Wk  = (const float*)d_in[2];
  const float* Wv  = (const float*)d_in[3];
  const float* Wo  = (const float*)d_in[4];

  char* ws = (char*)d_ws;
  size_t off = 0;
  unsigned short* hid_b = (unsigned short*)(ws + off); off += (size_t)2048 * 4096 * 2;
  unsigned short* QKV   = (unsigned short*)(ws + off); off += (size_t)2048 * 6144 * 2;
  unsigned short* Ob    = (unsigned short*)(ws + off); off += (size_t)2048 * 4096 * 2;

  cvt_hid<<<2048, 256, 0, stream>>>(hid, hid_b, 2048 * 4096);

  // fused QKV projection: B rows 0..4096 = Wq, ..5120 = Wk, ..6144 = Wv (f32, fused cvt)
  gemm_f32b<128, 192, true><<<dim3(32, 16), 256, 0, stream>>>(
      hid_b, Wq, Wk, Wv, 4096, 5120, (void*)QKV, 2048, 6144, 4096);

  rope_k<<<20480, 256, 0, stream>>>(QKV);

  attn_k<<<512, 512, 0, stream>>>(QKV, Ob);

  gemm_f32b<128, 128, false><<<dim3(32, 16), 256, 0, stream>>>(
      Ob, Wo, Wo, Wo, 4096, 4096, d_out, 2048, 4096, 4096);
}

// Round 15
// 328.483 us; speedup vs baseline: 1.4289x; 1.4289x over previous
//
#include <hip/hip_runtime.h>
#include <hip/hip_bf16.h>

typedef __attribute__((ext_vector_type(4))) float f32x4;
typedef __attribute__((ext_vector_type(8))) short short8;
typedef __attribute__((ext_vector_type(4))) unsigned int u32x4;

__device__ __forceinline__ unsigned short f2bf(float f) {
  union { float f; unsigned int u; } v; v.f = f;
  unsigned int r = (v.u + 0x7fffu + ((v.u >> 16) & 1u)) >> 16;
  return (unsigned short)r;
}
__device__ __forceinline__ unsigned short f2bf_fast(float f) {
  __hip_bfloat16 h = __float2bfloat16(f);
  return __builtin_bit_cast(unsigned short, h);
}
__device__ __forceinline__ float bf2f(unsigned short h) {
  union { unsigned int u; float f; } v; v.u = ((unsigned int)h) << 16;
  return v.f;
}
__device__ __forceinline__ unsigned int cvt_pk_bf16(float lo, float hi) {
  unsigned int r;
  asm("v_cvt_pk_bf16_f32 %0, %1, %2" : "=v"(r) : "v"(lo), "v"(hi));
  return r;
}

__device__ __forceinline__ void gload_lds16(const void* g, void* l) {
  __builtin_amdgcn_global_load_lds((const __attribute__((address_space(1))) void*)g,
                                   (__attribute__((address_space(3))) void*)l,
                                   16, 0, 0);
}

template <int N>
__device__ __forceinline__ void vmwait() {
  asm volatile("s_waitcnt vmcnt(%0)" :: "n"(N) : "memory");
}

// ---------------- fused f32 -> bf16 convert: hid + Wq + Wk + Wv ----------------
// outputs contiguous in ws: [hid(8.4M el) Wq(16.8M) Wk(4.2M) Wv(4.2M)]
__global__ __launch_bounds__(256) void cvt_all(
    const float* __restrict__ hid, const float* __restrict__ wq,
    const float* __restrict__ wk, const float* __restrict__ wv,
    unsigned short* __restrict__ out) {
  const size_t E0 = 8388608, E1 = 25165824, E2 = 29360128, E3 = 33554432;
  size_t stride = (size_t)gridDim.x * blockDim.x;
  for (size_t i = (size_t)blockIdx.x * blockDim.x + threadIdx.x; i * 4 < E3; i += stride) {
    size_t i4 = i * 4;
    const float* src; size_t rel;
    if (i4 < E0)      { src = hid; rel = i4; }
    else if (i4 < E1) { src = wq;  rel = i4 - E0; }
    else if (i4 < E2) { src = wk;  rel = i4 - E1; }
    else              { src = wv;  rel = i4 - E2; }
    float4 v = *(const float4*)(src + rel);
    ushort4 o;
    o.x = f2bf(v.x); o.y = f2bf(v.y); o.z = f2bf(v.z); o.w = f2bf(v.w);
    *(ushort4*)(out + i4) = o;
  }
}

// ---------------- BK=64 double-buffered bf16 GEMM (round-11 verbatim) ----------------
template <int BM, int BN, bool BF16_OUT>
__global__ __launch_bounds__(256, 2) void gemm_p2(
    const unsigned short* __restrict__ A,
    const unsigned short* __restrict__ B,
    void* __restrict__ Cout, int M, int N, int K) {
  constexpr int BK = 64;
  constexpr int MFRAG = BM / 32;
  constexpr int NFRAG = BN / 32;
  constexpr int ASH = BM * BK;
  constexpr int BSH = BN * BK;
  constexpr int BUF = ASH + BSH;
  constexpr int ALOADS = BM / 32;
  constexpr int BLOADS = BN / 32;
  __shared__ unsigned short lds[2 * BUF];

  const int tid = threadIdx.x;
  const int wave = tid >> 6, lane = tid & 63;
  const int l15 = lane & 15, l4 = lane >> 4;
  const int row0 = blockIdx.y * BM, col0 = blockIdx.x * BN;
  const int mrow0 = (wave >> 1) * (BM / 2);
  const int ncol0 = (wave & 1) * (BN / 2);
  const int NT = K >> 6;
  const int srow = tid >> 3;
  const int scol = ((tid & 7) ^ (srow & 7)) * 8;

  f32x4 zv = {0.f, 0.f, 0.f, 0.f};
  f32x4 acc[MFRAG][NFRAG];
#pragma unroll
  for (int m = 0; m < MFRAG; ++m)
#pragma unroll
    for (int n = 0; n < NFRAG; ++n) acc[m][n] = zv;

  auto stage = [&](int t) {
    unsigned short* buf = &lds[(t & 1) * BUF];
    const int k0 = t * BK;
#pragma unroll
    for (int i = 0; i < ALOADS; ++i)
      gload_lds16(A + (size_t)(row0 + i * 32 + srow) * K + k0 + scol,
                  buf + i * 2048 + tid * 8);
#pragma unroll
    for (int i = 0; i < BLOADS; ++i)
      gload_lds16(B + (size_t)(col0 + i * 32 + srow) * K + k0 + scol,
                  buf + ASH + i * 2048 + tid * 8);
  };

  stage(0);

  for (int t = 0; t < NT; ++t) {
    vmwait<0>();
    __builtin_amdgcn_sched_barrier(0);
    __builtin_amdgcn_s_barrier();
    __builtin_amdgcn_sched_barrier(0);
    if (t + 1 < NT) stage(t + 1);

    const unsigned short* Ab = &lds[(t & 1) * BUF];
    const unsigned short* Bb = Ab + ASH;
#pragma unroll
    for (int h = 0; h < 2; ++h) {
      short8 afr[MFRAG], bfr[NFRAG];
#pragma unroll
      for (int m = 0; m < MFRAG; ++m) {
        int row = mrow0 + m * 16 + l15;
        afr[m] = *(const short8*)&Ab[row * 64 + (((h * 4 + l4) ^ (l15 & 7)) * 8)];
      }
#pragma unroll
      for (int n = 0; n < NFRAG; ++n) {
        int row = ncol0 + n * 16 + l15;
        bfr[n] = *(const short8*)&Bb[row * 64 + (((h * 4 + l4) ^ (l15 & 7)) * 8)];
      }
      __builtin_amdgcn_s_setprio(1);
#pragma unroll
      for (int m = 0; m < MFRAG; ++m)
#pragma unroll
        for (int n = 0; n < NFRAG; ++n)
          acc[m][n] = __builtin_amdgcn_mfma_f32_16x16x32_bf16(afr[m], bfr[n], acc[m][n], 0, 0, 0);
      __builtin_amdgcn_s_setprio(0);
    }
    __builtin_amdgcn_sched_barrier(0);
  }

#pragma unroll
  for (int m = 0; m < MFRAG; ++m)
#pragma unroll
    for (int n = 0; n < NFRAG; ++n)
#pragma unroll
      for (int j = 0; j < 4; ++j) {
        int r = row0 + mrow0 + m * 16 + l4 * 4 + j;
        int cc = col0 + ncol0 + n * 16 + l15;
        if constexpr (BF16_OUT)
          ((unsigned short*)Cout)[(size_t)r * N + cc] = f2bf(acc[m][n][j]);
        else
          ((float*)Cout)[(size_t)r * N + cc] = acc[m][n][j];
      }
}

// ---------------- BK=64 dbuf GEMM, f32 B with fused convert (round-13 verbatim, 1-deep) ----------------
template <int BM, int BN, bool BF16_OUT>
__global__ __launch_bounds__(256, 2) void gemm_f32b(
    const unsigned short* __restrict__ A,
    const float* __restrict__ B0, const float* __restrict__ B1,
    const float* __restrict__ B2, int b1, int b2,
    void* __restrict__ Cout, int M, int N, int K) {
  constexpr int BK = 64;
  constexpr int MFRAG = BM / 32;
  constexpr int NFRAG = BN / 32;
  constexpr int ASH = BM * BK;
  constexpr int BSH = BN * BK;
  constexpr int BUF = ASH + BSH;
  constexpr int ALOADS = BM / 32;
  constexpr int BLOADS = BN / 32;
  __shared__ unsigned short lds[2 * BUF];

  const int tid = threadIdx.x;
  const int wave = tid >> 6, lane = tid & 63;
  const int l15 = lane & 15, l4 = lane >> 4;
  const int row0 = blockIdx.y * BM, col0 = blockIdx.x * BN;
  const int mrow0 = (wave >> 1) * (BM / 2);
  const int ncol0 = (wave & 1) * (BN / 2);
  const int NT = K >> 6;
  const int srow = tid >> 3;
  const int spsw = (tid & 7) ^ (srow & 7);

  f32x4 zv = {0.f, 0.f, 0.f, 0.f};
  f32x4 acc[MFRAG][NFRAG];
#pragma unroll
  for (int m = 0; m < MFRAG; ++m)
#pragma unroll
    for (int n = 0; n < NFRAG; ++n) acc[m][n] = zv;

  float4 br[2 * BLOADS];

  auto stageA = [&](int t) {
    unsigned short* buf = &lds[(t & 1) * BUF];
    const int k0 = t * BK;
#pragma unroll
    for (int i = 0; i < ALOADS; ++i)
      gload_lds16(A + (size_t)(row0 + i * 32 + srow) * K + k0 + spsw * 8,
                  buf + i * 2048 + tid * 8);
  };
  auto loadB = [&](int t) {
    const int k0 = t * BK;
#pragma unroll
    for (int i = 0; i < BLOADS; ++i) {
      int grow = col0 + i * 32;
      const float* src; int rrow;
      if (grow < b1)      { src = B0; rrow = grow; }
      else if (grow < b2) { src = B1; rrow = grow - b1; }
      else                { src = B2; rrow = grow - b2; }
      const float* p = src + (size_t)(rrow + srow) * K + k0 + spsw * 8;
      br[2 * i]     = *(const float4*)p;
      br[2 * i + 1] = *(const float4*)(p + 4);
    }
  };
  auto writeB = [&](int t) {
    unsigned short* buf = &lds[(t & 1) * BUF];
#pragma unroll
    for (int i = 0; i < BLOADS; ++i) {
      u32x4 w;
      w[0] = cvt_pk_bf16(br[2 * i].x, br[2 * i].y);
      w[1] = cvt_pk_bf16(br[2 * i].z, br[2 * i].w);
      w[2] = cvt_pk_bf16(br[2 * i + 1].x, br[2 * i + 1].y);
      w[3] = cvt_pk_bf16(br[2 * i + 1].z, br[2 * i + 1].w);
      *(u32x4*)&buf[ASH + i * 2048 + tid * 8] = w;
    }
  };

  stageA(0);
  loadB(0);
  vmwait<0>();
  writeB(0);

  for (int t = 0; t < NT; ++t) {
    asm volatile("s_waitcnt lgkmcnt(0)" ::: "memory");
    __builtin_amdgcn_sched_barrier(0);
    __builtin_amdgcn_s_barrier();
    __builtin_amdgcn_sched_barrier(0);
    const bool hn = (t + 1 < NT);
    if (hn) { stageA(t + 1); loadB(t + 1); }

    const unsigned short* Ab = &lds[(t & 1) * BUF];
    const unsigned short* Bb = Ab + ASH;
#pragma unroll
    for (int h = 0; h < 2; ++h) {
      short8 afr[MFRAG], bfr[NFRAG];
#pragma unroll
      for (int m = 0; m < MFRAG; ++m) {
        int row = mrow0 + m * 16 + l15;
        afr[m] = *(const short8*)&Ab[row * 64 + (((h * 4 + l4) ^ (l15 & 7)) * 8)];
      }
#pragma unroll
      for (int n = 0; n < NFRAG; ++n) {
        int row = ncol0 + n * 16 + l15;
        bfr[n] = *(const short8*)&Bb[row * 64 + (((h * 4 + l4) ^ (l15 & 7)) * 8)];
      }
      __builtin_amdgcn_s_setprio(1);
#pragma unroll
      for (int m = 0; m < MFRAG; ++m)
#pragma unroll
        for (int n = 0; n < NFRAG; ++n)
          acc[m][n] = __builtin_amdgcn_mfma_f32_16x16x32_bf16(afr[m], bfr[n], acc[m][n], 0, 0, 0);
      __builtin_amdgcn_s_setprio(0);
    }

    if (hn) {
      vmwait<0>();
      __builtin_amdgcn_sched_barrier(0);
      writeB(t + 1);
    }
  }

#pragma unroll
  for (int m = 0; m < MFRAG; ++m)
#pragma unroll
    for (int n = 0; n < NFRAG; ++n)
#pragma unroll
      for (int j = 0; j < 4; ++j) {
        int r = row0 + mrow0 + m * 16 + l4 * 4 + j;
        int cc = col0 + ncol0 + n * 16 + l15;
        if constexpr (BF16_OUT)
          ((unsigned short*)Cout)[(size_t)r * N + cc] = f2bf(acc[m][n][j]);
        else
          ((float*)Cout)[(size_t)r * N + cc] = acc[m][n][j];
      }
}

// ---------------- RoPE (in-place on fused QKV [2048][6144]) ----------------
__global__ __launch_bounds__(256) void rope_k(unsigned short* __restrict__ QKV) {
  int idx = blockIdx.x * blockDim.x + threadIdx.x;
  if (idx >= 2048 * 40 * 64) return;
  int j = idx & 63;
  int rest = idx >> 6;
  int slot = rest % 40;
  int s = rest / 40;
  int doff = (slot < 32) ? slot * 128 : 4096 + (slot - 32) * 128;
  unsigned short* p = QKV + (size_t)s * 6144 + doff;
  float inv = exp2f((float)j * -0.20762050593046015f);
  float ang = (float)s * inv;
  float sn, cs;
  sincosf(ang, &sn, &cs);
  float x1 = bf2f(p[j]), x2 = bf2f(p[j + 64]);
  p[j]      = f2bf(x1 * cs - x2 * sn);
  p[j + 64] = f2bf(x2 * cs + x1 * sn);
}

// ---------------- causal GQA flash attention (round-11 verbatim: 106us, VGPR 64) ----------------
__global__ __launch_bounds__(512, 4) void attn_k(
    const unsigned short* __restrict__ QKV,  // [2048][6144]
    unsigned short* __restrict__ O) {        // [2048][4096]
  __shared__ unsigned short Ks[2][64 * 128];
  __shared__ unsigned short Vs[2][64 * 128];

  const int tid = threadIdx.x;
  const int wave = tid >> 6, lane = tid & 63;
  const int l15 = lane & 15, l4 = lane >> 4;

  const int bid = blockIdx.x;
  const int qt16 = bid & 15;
  const int h = (bid >> 4) & 31;
  const int qt = (h < 16) ? (15 - qt16) : qt16;
  const int hkv = h >> 2;
  const int q0 = qt * 128;
  const int qrow = q0 + wave * 16 + l15;
  const float C2 = 0.12751744219938793f;  // log2(e)/sqrt(128)

  const unsigned short* Qp = QKV + h * 128;
  const unsigned short* Kp = QKV + 4096 + hkv * 128;
  const unsigned short* Vp = QKV + 5120 + hkv * 128;

  const int vpr = tid >> 4;
  const int vd8 = tid & 15;
  const int vg8 = vpr >> 2, vjj = 2 * (vpr & 3);
  const int vn = vd8 >> 1, vch = (vd8 & 1) * 8;

  short8 qf[4];
#pragma unroll
  for (int kc = 0; kc < 4; ++kc)
    qf[kc] = *(const short8*)(Qp + (size_t)qrow * 6144 + kc * 32 + l4 * 8);

  f32x4 zv = {0.f, 0.f, 0.f, 0.f};
  f32x4 oacc[8];
#pragma unroll
  for (int n = 0; n < 8; ++n) oacc[n] = zv;
  float mrow = -3.0e38f, lrow = 0.f;

  auto stageK = [&](int kvn, int b) {
#pragma unroll
    for (int i = 0; i < 2; ++i) {
      int c = wave * 2 + i;
      int row = c * 4 + l4;
      int colel = (l15 * 8) ^ ((row & 7) << 3);
      gload_lds16(Kp + (size_t)(kvn + row) * 6144 + colel, &Ks[b][c * 512]);
    }
  };
  auto loadV = [&](int kvn, short8& va, short8& vb) {
    va = *(const short8*)(Vp + (size_t)(kvn + 2 * vpr) * 6144 + vd8 * 8);
    vb = *(const short8*)(Vp + (size_t)(kvn + 2 * vpr + 1) * 6144 + vd8 * 8);
  };
  auto writeV = [&](int b, const short8& va, const short8& vb) {
#pragma unroll
    for (int i = 0; i < 8; ++i) {
      int c = vch + i;
      unsigned int pack = (unsigned int)(unsigned short)va[i] |
                          ((unsigned int)(unsigned short)vb[i] << 16);
      *(unsigned int*)&Vs[b][vg8 * 1024 + vn * 128 + ((c ^ vn) & 15) * 8 + vjj] = pack;
    }
  };

  {
    short8 va, vb;
    stageK(0, 0);
    loadV(0, va, vb);
    writeV(0, va, vb);
  }
  __syncthreads();

  const int nt = 2 * qt + 2;
  for (int t = 0; t < nt; ++t) {
    const int cur = t & 1, nxt = cur ^ 1;
    const int kv0 = t * 64;
    const bool has_next = (t + 1 < nt);
    short8 va, vb;
    if (has_next) {
      stageK(kv0 + 64, nxt);
      loadV(kv0 + 64, va, vb);
    }

    f32x4 sacc[4];
#pragma unroll
    for (int cb = 0; cb < 4; ++cb) sacc[cb] = zv;
    __builtin_amdgcn_s_setprio(1);
#pragma unroll
    for (int cb = 0; cb < 4; ++cb) {
      int row = cb * 16 + l15;
      int sw = (row & 7) << 3;
#pragma unroll
      for (int kc = 0; kc < 4; ++kc) {
        short8 kf = *(const short8*)&Ks[cur][row * 128 + ((kc * 32 + l4 * 8) ^ sw)];
        sacc[cb] = __builtin_amdgcn_mfma_f32_16x16x32_bf16(kf, qf[kc], sacc[cb], 0, 0, 0);
      }
    }
    __builtin_amdgcn_s_setprio(0);

    if (kv0 + 63 > q0 + wave * 16) {
#pragma unroll
      for (int cb = 0; cb < 4; ++cb)
#pragma unroll
        for (int j = 0; j < 4; ++j) {
          int kvpos = kv0 + cb * 16 + l4 * 4 + j;
          if (kvpos > qrow) sacc[cb][j] = -3.0e38f;
        }
    }

    float pm = sacc[0][0];
#pragma unroll
    for (int cb = 0; cb < 4; ++cb)
#pragma unroll
      for (int j = 0; j < 4; ++j) pm = fmaxf(pm, sacc[cb][j]);
    pm = fmaxf(pm, __shfl_xor(pm, 16, 64));
    pm = fmaxf(pm, __shfl_xor(pm, 32, 64));

    if (__any(pm > mrow + 64.0f)) {
      float mn = fmaxf(mrow, pm);
      float rs = exp2f((mrow - mn) * C2);
      mrow = mn;
      lrow *= rs;
      float rs0 = __shfl(rs, 4 * l4 + 0, 64);
      float rs1 = __shfl(rs, 4 * l4 + 1, 64);
      float rs2 = __shfl(rs, 4 * l4 + 2, 64);
      float rs3 = __shfl(rs, 4 * l4 + 3, 64);
#pragma unroll
      for (int n = 0; n < 8; ++n) {
        oacc[n][0] *= rs0; oacc[n][1] *= rs1;
        oacc[n][2] *= rs2; oacc[n][3] *= rs3;
      }
    }

    unsigned int pack[8];
    float psum = 0.f;
#pragma unroll
    for (int cb = 0; cb < 4; ++cb) {
      float p0 = exp2f((sacc[cb][0] - mrow) * C2);
      float p1 = exp2f((sacc[cb][1] - mrow) * C2);
      float p2 = exp2f((sacc[cb][2] - mrow) * C2);
      float p3 = exp2f((sacc[cb][3] - mrow) * C2);
      psum += (p0 + p1) + (p2 + p3);
      pack[cb * 2 + 0] = cvt_pk_bf16(p0, p1);
      pack[cb * 2 + 1] = cvt_pk_bf16(p2, p3);
    }
    lrow += psum;

#pragma unroll
    for (int ks = 0; ks < 2; ++ks) {
      u32x4 pw;
#pragma unroll
      for (int w = 0; w < 4; ++w) {
        int sl = l15 + 16 * ((2 * l4 + (w >> 1)) & 3);
        int v0 = __shfl((int)pack[4 * ks + (w & 1)], sl, 64);
        int v1 = __shfl((int)pack[4 * ks + 2 + (w & 1)], sl, 64);
        pw[w] = (lane < 32) ? (unsigned int)v0 : (unsigned int)v1;
      }
      short8 pf = __builtin_bit_cast(short8, pw);
      __builtin_amdgcn_s_setprio(1);
#pragma unroll
      for (int n = 0; n < 8; ++n) {
        short8 vf = *(const short8*)&Vs[cur][(ks * 4 + l4) * 1024 + n * 128 + ((l15 ^ n) & 15) * 8];
        oacc[n] = __builtin_amdgcn_mfma_f32_16x16x32_bf16(pf, vf, oacc[n], 0, 0, 0);
      }
      __builtin_amdgcn_s_setprio(0);
    }

    if (has_next) writeV(nxt, va, vb);
    __syncthreads();
  }

  lrow += __shfl_xor(lrow, 16, 64);
  lrow += __shfl_xor(lrow, 32, 64);
  float linv = 1.0f / lrow;
  float li0 = __shfl(linv, 4 * l4 + 0, 64);
  float li1 = __shfl(linv, 4 * l4 + 1, 64);
  float li2 = __shfl(linv, 4 * l4 + 2, 64);
  float li3 = __shfl(linv, 4 * l4 + 3, 64);
#pragma unroll
  for (int n = 0; n < 8; ++n) {
    int r = q0 + wave * 16 + l4 * 4;
    size_t base = (size_t)r * 4096 + h * 128 + n * 16 + l15;
    O[base]          = f2bf_fast(oacc[n][0] * li0);
    O[base + 4096]   = f2bf_fast(oacc[n][1] * li1);
    O[base + 8192]   = f2bf_fast(oacc[n][2] * li2);
    O[base + 12288]  = f2bf_fast(oacc[n][3] * li3);
  }
}

extern "C" void kernel_launch(void* const* d_in, const int* in_sizes, int n_in,
                              void* d_out, int out_size, void* d_ws, size_t ws_size,
                              hipStream_t stream) {
  const float* hid = (const float*)d_in[0];
  const float* Wq  = (const float*)d_in[1];
  const float* Wk  = (const float*)d_in[2];
  const float* Wv  = (const float*)d_in[3];
  const float* Wo  = (const float*)d_in[4];

  char* ws = (char*)d_ws;
  size_t off = 0;
  unsigned short* hid_b = (unsigned short*)(ws + off); off += (size_t)2048 * 4096 * 2;
  unsigned short* Wq_b  = (unsigned short*)(ws + off); off += (size_t)4096 * 4096 * 2;
  unsigned short* Wk_b  = (unsigned short*)(ws + off); off += (size_t)1024 * 4096 * 2;
  unsigned short* Wv_b  = (unsigned short*)(ws + off); off += (size_t)1024 * 4096 * 2;
  unsigned short* QKV   = (unsigned short*)(ws + off); off += (size_t)2048 * 6144 * 2;
  unsigned short* Ob    = (unsigned short*)(ws + off); off += (size_t)2048 * 4096 * 2;
  (void)Wk_b; (void)Wv_b;

  // convert hid + Wq + Wk + Wv (Wo consumed as f32 by the O-proj GEMM)
  cvt_all<<<4096, 256, 0, stream>>>(hid, Wq, Wk, Wv, hid_b);

  // fused QKV projection: B = [Wq; Wk; Wv] contiguous bf16, N = 6144 (round-11 kernel)
  gemm_p2<128, 192, true><<<dim3(32, 16), 256, 0, stream>>>(hid_b, Wq_b, (void*)QKV, 2048, 6144, 4096);

  rope_k<<<20480, 256, 0, stream>>>(QKV);

  attn_k<<<512, 512, 0, stream>>>(QKV, Ob);

  // O projection reads Wo f32 directly (round-13 kernel, 1-deep; no Wo conversion pass)
  gemm_f32b<128, 128, false><<<dim3(32, 16), 256, 0, stream>>>(
      Ob, Wo, Wo, Wo, 4096, 4096, d_out, 2048, 4096, 4096);
}

// Round 16
// 306.716 us; speedup vs baseline: 1.5303x; 1.0710x over previous
//
#include <hip/hip_runtime.h>
#include <hip/hip_bf16.h>

typedef __attribute__((ext_vector_type(4))) float f32x4;
typedef __attribute__((ext_vector_type(8))) short short8;
typedef __attribute__((ext_vector_type(4))) unsigned int u32x4;

__device__ __forceinline__ unsigned short f2bf(float f) {
  union { float f; unsigned int u; } v; v.f = f;
  unsigned int r = (v.u + 0x7fffu + ((v.u >> 16) & 1u)) >> 16;
  return (unsigned short)r;
}
__device__ __forceinline__ unsigned short f2bf_fast(float f) {
  __hip_bfloat16 h = __float2bfloat16(f);
  return __builtin_bit_cast(unsigned short, h);
}
__device__ __forceinline__ float bf2f(unsigned short h) {
  union { unsigned int u; float f; } v; v.u = ((unsigned int)h) << 16;
  return v.f;
}
__device__ __forceinline__ unsigned int cvt_pk_bf16(float lo, float hi) {
  unsigned int r;
  asm("v_cvt_pk_bf16_f32 %0, %1, %2" : "=v"(r) : "v"(lo), "v"(hi));
  return r;
}

__device__ __forceinline__ void gload_lds16(const void* g, void* l) {
  __builtin_amdgcn_global_load_lds((const __attribute__((address_space(1))) void*)g,
                                   (__attribute__((address_space(3))) void*)l,
                                   16, 0, 0);
}

template <int N>
__device__ __forceinline__ void vmwait() {
  asm volatile("s_waitcnt vmcnt(%0)" :: "n"(N) : "memory");
}

// ---------------- fused f32 -> bf16 convert for all 5 inputs (round-11 verbatim) ----------------
__global__ __launch_bounds__(256) void cvt_all(
    const float* __restrict__ hid, const float* __restrict__ wq,
    const float* __restrict__ wk, const float* __restrict__ wv,
    const float* __restrict__ wo, unsigned short* __restrict__ out) {
  const size_t E0 = 8388608, E1 = 25165824, E2 = 29360128, E3 = 33554432, E4 = 50331648;
  size_t stride = (size_t)gridDim.x * blockDim.x;
  for (size_t i = (size_t)blockIdx.x * blockDim.x + threadIdx.x; i * 4 < E4; i += stride) {
    size_t i4 = i * 4;
    const float* src; size_t rel;
    if (i4 < E0)      { src = hid; rel = i4; }
    else if (i4 < E1) { src = wq;  rel = i4 - E0; }
    else if (i4 < E2) { src = wk;  rel = i4 - E1; }
    else if (i4 < E3) { src = wv;  rel = i4 - E2; }
    else              { src = wo;  rel = i4 - E3; }
    float4 v = *(const float4*)(src + rel);
    ushort4 o;
    o.x = f2bf(v.x); o.y = f2bf(v.y); o.z = f2bf(v.z); o.w = f2bf(v.w);
    *(ushort4*)(out + i4) = o;
  }
}

// ---------------- BK=64 double-buffered bf16 GEMM (round-11 verbatim) ----------------
template <int BM, int BN, bool BF16_OUT>
__global__ __launch_bounds__(256, 2) void gemm_p2(
    const unsigned short* __restrict__ A,
    const unsigned short* __restrict__ B,
    void* __restrict__ Cout, int M, int N, int K) {
  constexpr int BK = 64;
  constexpr int MFRAG = BM / 32;
  constexpr int NFRAG = BN / 32;
  constexpr int ASH = BM * BK;
  constexpr int BSH = BN * BK;
  constexpr int BUF = ASH + BSH;
  constexpr int ALOADS = BM / 32;
  constexpr int BLOADS = BN / 32;
  __shared__ unsigned short lds[2 * BUF];

  const int tid = threadIdx.x;
  const int wave = tid >> 6, lane = tid & 63;
  const int l15 = lane & 15, l4 = lane >> 4;
  const int row0 = blockIdx.y * BM, col0 = blockIdx.x * BN;
  const int mrow0 = (wave >> 1) * (BM / 2);
  const int ncol0 = (wave & 1) * (BN / 2);
  const int NT = K >> 6;
  const int srow = tid >> 3;
  const int scol = ((tid & 7) ^ (srow & 7)) * 8;

  f32x4 zv = {0.f, 0.f, 0.f, 0.f};
  f32x4 acc[MFRAG][NFRAG];
#pragma unroll
  for (int m = 0; m < MFRAG; ++m)
#pragma unroll
    for (int n = 0; n < NFRAG; ++n) acc[m][n] = zv;

  auto stage = [&](int t) {
    unsigned short* buf = &lds[(t & 1) * BUF];
    const int k0 = t * BK;
#pragma unroll
    for (int i = 0; i < ALOADS; ++i)
      gload_lds16(A + (size_t)(row0 + i * 32 + srow) * K + k0 + scol,
                  buf + i * 2048 + tid * 8);
#pragma unroll
    for (int i = 0; i < BLOADS; ++i)
      gload_lds16(B + (size_t)(col0 + i * 32 + srow) * K + k0 + scol,
                  buf + ASH + i * 2048 + tid * 8);
  };

  stage(0);

  for (int t = 0; t < NT; ++t) {
    vmwait<0>();
    __builtin_amdgcn_sched_barrier(0);
    __builtin_amdgcn_s_barrier();
    __builtin_amdgcn_sched_barrier(0);
    if (t + 1 < NT) stage(t + 1);

    const unsigned short* Ab = &lds[(t & 1) * BUF];
    const unsigned short* Bb = Ab + ASH;
#pragma unroll
    for (int h = 0; h < 2; ++h) {
      short8 afr[MFRAG], bfr[NFRAG];
#pragma unroll
      for (int m = 0; m < MFRAG; ++m) {
        int row = mrow0 + m * 16 + l15;
        afr[m] = *(const short8*)&Ab[row * 64 + (((h * 4 + l4) ^ (l15 & 7)) * 8)];
      }
#pragma unroll
      for (int n = 0; n < NFRAG; ++n) {
        int row = ncol0 + n * 16 + l15;
        bfr[n] = *(const short8*)&Bb[row * 64 + (((h * 4 + l4) ^ (l15 & 7)) * 8)];
      }
      __builtin_amdgcn_s_setprio(1);
#pragma unroll
      for (int m = 0; m < MFRAG; ++m)
#pragma unroll
        for (int n = 0; n < NFRAG; ++n)
          acc[m][n] = __builtin_amdgcn_mfma_f32_16x16x32_bf16(afr[m], bfr[n], acc[m][n], 0, 0, 0);
      __builtin_amdgcn_s_setprio(0);
    }
    __builtin_amdgcn_sched_barrier(0);
  }

#pragma unroll
  for (int m = 0; m < MFRAG; ++m)
#pragma unroll
    for (int n = 0; n < NFRAG; ++n)
#pragma unroll
      for (int j = 0; j < 4; ++j) {
        int r = row0 + mrow0 + m * 16 + l4 * 4 + j;
        int cc = col0 + ncol0 + n * 16 + l15;
        if constexpr (BF16_OUT)
          ((unsigned short*)Cout)[(size_t)r * N + cc] = f2bf(acc[m][n][j]);
        else
          ((float*)Cout)[(size_t)r * N + cc] = acc[m][n][j];
      }
}

// ---------------- RoPE (in-place on fused QKV [2048][6144]) ----------------
__global__ __launch_bounds__(256) void rope_k(unsigned short* __restrict__ QKV) {
  int idx = blockIdx.x * blockDim.x + threadIdx.x;
  if (idx >= 2048 * 40 * 64) return;
  int j = idx & 63;
  int rest = idx >> 6;
  int slot = rest % 40;
  int s = rest / 40;
  int doff = (slot < 32) ? slot * 128 : 4096 + (slot - 32) * 128;
  unsigned short* p = QKV + (size_t)s * 6144 + doff;
  float inv = exp2f((float)j * -0.20762050593046015f);
  float ang = (float)s * inv;
  float sn, cs;
  sincosf(ang, &sn, &cs);
  float x1 = bf2f(p[j]), x2 = bf2f(p[j + 64]);
  p[j]      = f2bf(x1 * cs - x2 * sn);
  p[j + 64] = f2bf(x2 * cs + x1 * sn);
}

// ---------------- causal GQA flash attention, KV-SPLIT partials ----------------
// grid 1024: bid -> qt = 15-(bid>>6) (LPT), h = (bid&63)>>1, half = bid&1.
// Block processes kv-tiles [half*(qt+1), (half+1)*(qt+1)) of row-block qt.
// Inner loop byte-identical to the round-11 106us kernel. Epilogue writes
// normalized O partial (bf16) to Opart[half] and per-row (m,l) to ML.
// 1024 blocks > 512 residency slots -> backfill queue fixes the 26% occupancy.
__global__ __launch_bounds__(512, 4) void attn_part(
    const unsigned short* __restrict__ QKV,  // [2048][6144]
    unsigned short* __restrict__ Opart,      // [2][2048][4096]
    float* __restrict__ ML) {                // [2][2048][32][2]
  __shared__ unsigned short Ks[2][64 * 128];
  __shared__ unsigned short Vs[2][64 * 128];

  const int tid = threadIdx.x;
  const int wave = tid >> 6, lane = tid & 63;
  const int l15 = lane & 15, l4 = lane >> 4;

  const int bid = blockIdx.x;
  const int qt = 15 - (bid >> 6);
  const int rest = bid & 63;
  const int h = rest >> 1;
  const int half = rest & 1;
  const int hkv = h >> 2;
  const int q0 = qt * 128;
  const int qrow = q0 + wave * 16 + l15;
  const float C2 = 0.12751744219938793f;  // log2(e)/sqrt(128)

  const unsigned short* Qp = QKV + h * 128;
  const unsigned short* Kp = QKV + 4096 + hkv * 128;
  const unsigned short* Vp = QKV + 5120 + hkv * 128;

  const int vpr = tid >> 4;
  const int vd8 = tid & 15;
  const int vg8 = vpr >> 2, vjj = 2 * (vpr & 3);
  const int vn = vd8 >> 1, vch = (vd8 & 1) * 8;

  short8 qf[4];
#pragma unroll
  for (int kc = 0; kc < 4; ++kc)
    qf[kc] = *(const short8*)(Qp + (size_t)qrow * 6144 + kc * 32 + l4 * 8);

  f32x4 zv = {0.f, 0.f, 0.f, 0.f};
  f32x4 oacc[8];
#pragma unroll
  for (int n = 0; n < 8; ++n) oacc[n] = zv;
  float mrow = -3.0e38f, lrow = 0.f;

  auto stageK = [&](int kvn, int b) {
#pragma unroll
    for (int i = 0; i < 2; ++i) {
      int c = wave * 2 + i;
      int row = c * 4 + l4;
      int colel = (l15 * 8) ^ ((row & 7) << 3);
      gload_lds16(Kp + (size_t)(kvn + row) * 6144 + colel, &Ks[b][c * 512]);
    }
  };
  auto loadV = [&](int kvn, short8& va, short8& vb) {
    va = *(const short8*)(Vp + (size_t)(kvn + 2 * vpr) * 6144 + vd8 * 8);
    vb = *(const short8*)(Vp + (size_t)(kvn + 2 * vpr + 1) * 6144 + vd8 * 8);
  };
  auto writeV = [&](int b, const short8& va, const short8& vb) {
#pragma unroll
    for (int i = 0; i < 8; ++i) {
      int c = vch + i;
      unsigned int pack = (unsigned int)(unsigned short)va[i] |
                          ((unsigned int)(unsigned short)vb[i] << 16);
      *(unsigned int*)&Vs[b][vg8 * 1024 + vn * 128 + ((c ^ vn) & 15) * 8 + vjj] = pack;
    }
  };

  const int t0 = half * (qt + 1);
  const int t1 = t0 + (qt + 1);

  {
    short8 va, vb;
    stageK(t0 * 64, t0 & 1);
    loadV(t0 * 64, va, vb);
    writeV(t0 & 1, va, vb);
  }
  __syncthreads();

  for (int t = t0; t < t1; ++t) {
    const int cur = t & 1, nxt = cur ^ 1;
    const int kv0 = t * 64;
    const bool has_next = (t + 1 < t1);
    short8 va, vb;
    if (has_next) {
      stageK(kv0 + 64, nxt);
      loadV(kv0 + 64, va, vb);
    }

    f32x4 sacc[4];
#pragma unroll
    for (int cb = 0; cb < 4; ++cb) sacc[cb] = zv;
    __builtin_amdgcn_s_setprio(1);
#pragma unroll
    for (int cb = 0; cb < 4; ++cb) {
      int row = cb * 16 + l15;
      int sw = (row & 7) << 3;
#pragma unroll
      for (int kc = 0; kc < 4; ++kc) {
        short8 kf = *(const short8*)&Ks[cur][row * 128 + ((kc * 32 + l4 * 8) ^ sw)];
        sacc[cb] = __builtin_amdgcn_mfma_f32_16x16x32_bf16(kf, qf[kc], sacc[cb], 0, 0, 0);
      }
    }
    __builtin_amdgcn_s_setprio(0);

    if (kv0 + 63 > q0 + wave * 16) {
#pragma unroll
      for (int cb = 0; cb < 4; ++cb)
#pragma unroll
        for (int j = 0; j < 4; ++j) {
          int kvpos = kv0 + cb * 16 + l4 * 4 + j;
          if (kvpos > qrow) sacc[cb][j] = -3.0e38f;
        }
    }

    float pm = sacc[0][0];
#pragma unroll
    for (int cb = 0; cb < 4; ++cb)
#pragma unroll
      for (int j = 0; j < 4; ++j) pm = fmaxf(pm, sacc[cb][j]);
    pm = fmaxf(pm, __shfl_xor(pm, 16, 64));
    pm = fmaxf(pm, __shfl_xor(pm, 32, 64));

    if (__any(pm > mrow + 64.0f)) {
      float mn = fmaxf(mrow, pm);
      float rs = exp2f((mrow - mn) * C2);
      mrow = mn;
      lrow *= rs;
      float rs0 = __shfl(rs, 4 * l4 + 0, 64);
      float rs1 = __shfl(rs, 4 * l4 + 1, 64);
      float rs2 = __shfl(rs, 4 * l4 + 2, 64);
      float rs3 = __shfl(rs, 4 * l4 + 3, 64);
#pragma unroll
      for (int n = 0; n < 8; ++n) {
        oacc[n][0] *= rs0; oacc[n][1] *= rs1;
        oacc[n][2] *= rs2; oacc[n][3] *= rs3;
      }
    }

    unsigned int pack[8];
    float psum = 0.f;
#pragma unroll
    for (int cb = 0; cb < 4; ++cb) {
      float p0 = exp2f((sacc[cb][0] - mrow) * C2);
      float p1 = exp2f((sacc[cb][1] - mrow) * C2);
      float p2 = exp2f((sacc[cb][2] - mrow) * C2);
      float p3 = exp2f((sacc[cb][3] - mrow) * C2);
      psum += (p0 + p1) + (p2 + p3);
      pack[cb * 2 + 0] = cvt_pk_bf16(p0, p1);
      pack[cb * 2 + 1] = cvt_pk_bf16(p2, p3);
    }
    lrow += psum;

#pragma unroll
    for (int ks = 0; ks < 2; ++ks) {
      u32x4 pw;
#pragma unroll
      for (int w = 0; w < 4; ++w) {
        int sl = l15 + 16 * ((2 * l4 + (w >> 1)) & 3);
        int v0 = __shfl((int)pack[4 * ks + (w & 1)], sl, 64);
        int v1 = __shfl((int)pack[4 * ks + 2 + (w & 1)], sl, 64);
        pw[w] = (lane < 32) ? (unsigned int)v0 : (unsigned int)v1;
      }
      short8 pf = __builtin_bit_cast(short8, pw);
      __builtin_amdgcn_s_setprio(1);
#pragma unroll
      for (int n = 0; n < 8; ++n) {
        short8 vf = *(const short8*)&Vs[cur][(ks * 4 + l4) * 1024 + n * 128 + ((l15 ^ n) & 15) * 8];
        oacc[n] = __builtin_amdgcn_mfma_f32_16x16x32_bf16(pf, vf, oacc[n], 0, 0, 0);
      }
      __builtin_amdgcn_s_setprio(0);
    }

    if (has_next) writeV(nxt, va, vb);
    __syncthreads();
  }

  // ---- epilogue: reduce l, store (m,l) + normalized bf16 partial ----
  lrow += __shfl_xor(lrow, 16, 64);
  lrow += __shfl_xor(lrow, 32, 64);
  if (l4 == 0) {
    int r = q0 + wave * 16 + l15;
    *(float2*)&ML[((size_t)half * 2048 + r) * 64 + h * 2] = make_float2(mrow, lrow);
  }
  float linv = 1.0f / lrow;
  float li0 = __shfl(linv, 4 * l4 + 0, 64);
  float li1 = __shfl(linv, 4 * l4 + 1, 64);
  float li2 = __shfl(linv, 4 * l4 + 2, 64);
  float li3 = __shfl(linv, 4 * l4 + 3, 64);
  unsigned short* Oh = Opart + (size_t)half * 2048 * 4096;
#pragma unroll
  for (int n = 0; n < 8; ++n) {
    int r = q0 + wave * 16 + l4 * 4;
    size_t base = (size_t)r * 4096 + h * 128 + n * 16 + l15;
    Oh[base]          = f2bf_fast(oacc[n][0] * li0);
    Oh[base + 4096]   = f2bf_fast(oacc[n][1] * li1);
    Oh[base + 8192]   = f2bf_fast(oacc[n][2] * li2);
    Oh[base + 12288]  = f2bf_fast(oacc[n][3] * li3);
  }
}

// ---------------- merge the two KV-half partials ----------------
__global__ __launch_bounds__(256) void merge_k(
    const unsigned short* __restrict__ Opart, const float* __restrict__ ML,
    unsigned short* __restrict__ Ob) {
  int idx = blockIdx.x * 256 + threadIdx.x;
  int d8 = idx & 15;
  int rest = idx >> 4;
  int h = rest & 31;
  int r = rest >> 5;
  const float C2 = 0.12751744219938793f;
  float2 ml0 = *(const float2*)&ML[(size_t)r * 64 + h * 2];
  float2 ml1 = *(const float2*)&ML[((size_t)2048 + r) * 64 + h * 2];
  float m = fmaxf(ml0.x, ml1.x);
  float w0 = ml0.y * exp2f((ml0.x - m) * C2);
  float w1 = ml1.y * exp2f((ml1.x - m) * C2);
  float inv = 1.0f / (w0 + w1);
  w0 *= inv; w1 *= inv;
  size_t off = (size_t)r * 4096 + h * 128 + d8 * 8;
  short8 a = *(const short8*)(Opart + off);
  short8 b = *(const short8*)(Opart + (size_t)2048 * 4096 + off);
  short8 o;
#pragma unroll
  for (int i = 0; i < 8; ++i)
    o[i] = (short)f2bf_fast(w0 * bf2f((unsigned short)a[i]) + w1 * bf2f((unsigned short)b[i]));
  *(short8*)(Ob + off) = o;
}

extern "C" void kernel_launch(void* const* d_in, const int* in_sizes, int n_in,
                              void* d_out, int out_size, void* d_ws, size_t ws_size,
                              hipStream_t stream) {
  const float* hid = (const float*)d_in[0];
  const float* Wq  = (const float*)d_in[1];
  const float* Wk  = (const float*)d_in[2];
  const float* Wv  = (const float*)d_in[3];
  const float* Wo  = (const float*)d_in[4];

  char* ws = (char*)d_ws;
  size_t off = 0;
  unsigned short* hid_b = (unsigned short*)(ws + off); off += (size_t)2048 * 4096 * 2;
  unsigned short* Wq_b  = (unsigned short*)(ws + off); off += (size_t)4096 * 4096 * 2;
  unsigned short* Wk_b  = (unsigned short*)(ws + off); off += (size_t)1024 * 4096 * 2;
  unsigned short* Wv_b  = (unsigned short*)(ws + off); off += (size_t)1024 * 4096 * 2;
  unsigned short* Wo_b  = (unsigned short*)(ws + off); off += (size_t)4096 * 4096 * 2;
  unsigned short* QKV   = (unsigned short*)(ws + off); off += (size_t)2048 * 6144 * 2;
  unsigned short* Ob    = (unsigned short*)(ws + off); off += (size_t)2048 * 4096 * 2;
  (void)Wv_b;

  // Opart/ML alias Wq_b/Wk_b (dead after the QKV projection completes).
  unsigned short* Opart = Wq_b;            // 2*2048*4096*2B == Wq_b size exactly
  float*          MLb   = (float*)Wk_b;    // 2*2048*32*2*4B = 1MB << Wk_b

  cvt_all<<<4096, 256, 0, stream>>>(hid, Wq, Wk, Wv, Wo, hid_b);

  // fused QKV projection: B = [Wq; Wk; Wv] contiguous bf16, N = 6144
  gemm_p2<128, 192, true><<<dim3(32, 16), 256, 0, stream>>>(hid_b, Wq_b, (void*)QKV, 2048, 6144, 4096);

  rope_k<<<20480, 256, 0, stream>>>(QKV);

  // KV-split attention: 1024 partial blocks (LPT), then merge
  attn_part<<<1024, 512, 0, stream>>>(QKV, Opart, MLb);
  merge_k<<<4096, 256, 0, stream>>>(Opart, MLb, Ob);

  gemm_p2<128, 128, false><<<dim3(32, 16), 256, 0, stream>>>(Ob, Wo_b, d_out, 2048, 4096, 4096);
}

// Round 17
// 300.578 us; speedup vs baseline: 1.5615x; 1.0204x over previous
//
#include <hip/hip_runtime.h>
#include <hip/hip_bf16.h>

typedef __attribute__((ext_vector_type(4))) float f32x4;
typedef __attribute__((ext_vector_type(8))) short short8;
typedef __attribute__((ext_vector_type(4))) unsigned int u32x4;

__device__ __forceinline__ unsigned short f2bf(float f) {
  union { float f; unsigned int u; } v; v.f = f;
  unsigned int r = (v.u + 0x7fffu + ((v.u >> 16) & 1u)) >> 16;
  return (unsigned short)r;
}
__device__ __forceinline__ unsigned short f2bf_fast(float f) {
  __hip_bfloat16 h = __float2bfloat16(f);
  return __builtin_bit_cast(unsigned short, h);
}
__device__ __forceinline__ float bf2f(unsigned short h) {
  union { unsigned int u; float f; } v; v.u = ((unsigned int)h) << 16;
  return v.f;
}
__device__ __forceinline__ unsigned int cvt_pk_bf16(float lo, float hi) {
  unsigned int r;
  asm("v_cvt_pk_bf16_f32 %0, %1, %2" : "=v"(r) : "v"(lo), "v"(hi));
  return r;
}

__device__ __forceinline__ void gload_lds16(const void* g, void* l) {
  __builtin_amdgcn_global_load_lds((const __attribute__((address_space(1))) void*)g,
                                   (__attribute__((address_space(3))) void*)l,
                                   16, 0, 0);
}

template <int N>
__device__ __forceinline__ void vmwait() {
  asm volatile("s_waitcnt vmcnt(%0)" :: "n"(N) : "memory");
}
template <int N>
__device__ __forceinline__ void lgkmwait() {
  asm volatile("s_waitcnt lgkmcnt(%0)" :: "n"(N) : "memory");
}

// ---------------- fused f32 -> bf16 convert for all 5 inputs ----------------
__global__ __launch_bounds__(256) void cvt_all(
    const float* __restrict__ hid, const float* __restrict__ wq,
    const float* __restrict__ wk, const float* __restrict__ wv,
    const float* __restrict__ wo, unsigned short* __restrict__ out) {
  const size_t E0 = 8388608, E1 = 25165824, E2 = 29360128, E3 = 33554432, E4 = 50331648;
  size_t stride = (size_t)gridDim.x * blockDim.x;
  for (size_t i = (size_t)blockIdx.x * blockDim.x + threadIdx.x; i * 4 < E4; i += stride) {
    size_t i4 = i * 4;
    const float* src; size_t rel;
    if (i4 < E0)      { src = hid; rel = i4; }
    else if (i4 < E1) { src = wq;  rel = i4 - E0; }
    else if (i4 < E2) { src = wk;  rel = i4 - E1; }
    else if (i4 < E3) { src = wv;  rel = i4 - E2; }
    else              { src = wo;  rel = i4 - E3; }
    float4 v = *(const float4*)(src + rel);
    ushort4 o;
    o.x = f2bf(v.x); o.y = f2bf(v.y); o.z = f2bf(v.z); o.w = f2bf(v.w);
    *(ushort4*)(out + i4) = o;
  }
}

// ---------------- BK=64 double-buffered bf16 GEMM, cross-h pipelined reads ----------------
// Round-17 change vs round-16: all 2*(MFRAG+NFRAG) fragment reads issue up
// front (order pinned h0-group / h1-group via sched_barrier), then
// lgkmcnt(MFRAG+NFRAG) -> MFMA h0 overlaps h1's in-flight LDS reads ->
// lgkmcnt(0) -> MFMA h1. Fixes the measured MFMA/LDS pipe anti-overlap
// (r16: per-CU MFMA 1.86kcy + LDS 1.92kcy ~= measured 3.6kcy iter, i.e.
// serialized). sched_barrier(0) after each wait per rule #18.
template <int BM, int BN, bool BF16_OUT>
__global__ __launch_bounds__(256, 2) void gemm_p2(
    const unsigned short* __restrict__ A,
    const unsigned short* __restrict__ B,
    void* __restrict__ Cout, int M, int N, int K) {
  constexpr int BK = 64;
  constexpr int MFRAG = BM / 32;
  constexpr int NFRAG = BN / 32;
  constexpr int ASH = BM * BK;
  constexpr int BSH = BN * BK;
  constexpr int BUF = ASH + BSH;
  constexpr int ALOADS = BM / 32;
  constexpr int BLOADS = BN / 32;
  __shared__ unsigned short lds[2 * BUF];

  const int tid = threadIdx.x;
  const int wave = tid >> 6, lane = tid & 63;
  const int l15 = lane & 15, l4 = lane >> 4;
  const int row0 = blockIdx.y * BM, col0 = blockIdx.x * BN;
  const int mrow0 = (wave >> 1) * (BM / 2);
  const int ncol0 = (wave & 1) * (BN / 2);
  const int NT = K >> 6;
  const int srow = tid >> 3;
  const int scol = ((tid & 7) ^ (srow & 7)) * 8;

  f32x4 zv = {0.f, 0.f, 0.f, 0.f};
  f32x4 acc[MFRAG][NFRAG];
#pragma unroll
  for (int m = 0; m < MFRAG; ++m)
#pragma unroll
    for (int n = 0; n < NFRAG; ++n) acc[m][n] = zv;

  auto stage = [&](int t) {
    unsigned short* buf = &lds[(t & 1) * BUF];
    const int k0 = t * BK;
#pragma unroll
    for (int i = 0; i < ALOADS; ++i)
      gload_lds16(A + (size_t)(row0 + i * 32 + srow) * K + k0 + scol,
                  buf + i * 2048 + tid * 8);
#pragma unroll
    for (int i = 0; i < BLOADS; ++i)
      gload_lds16(B + (size_t)(col0 + i * 32 + srow) * K + k0 + scol,
                  buf + ASH + i * 2048 + tid * 8);
  };

  stage(0);

  for (int t = 0; t < NT; ++t) {
    vmwait<0>();
    __builtin_amdgcn_sched_barrier(0);
    __builtin_amdgcn_s_barrier();
    __builtin_amdgcn_sched_barrier(0);
    if (t + 1 < NT) stage(t + 1);

    const unsigned short* Ab = &lds[(t & 1) * BUF];
    const unsigned short* Bb = Ab + ASH;
    short8 afr0[MFRAG], bfr0[NFRAG], afr1[MFRAG], bfr1[NFRAG];
    // h0 fragment reads
#pragma unroll
    for (int m = 0; m < MFRAG; ++m) {
      int row = mrow0 + m * 16 + l15;
      afr0[m] = *(const short8*)&Ab[row * 64 + ((l4 ^ (l15 & 7)) * 8)];
    }
#pragma unroll
    for (int n = 0; n < NFRAG; ++n) {
      int row = ncol0 + n * 16 + l15;
      bfr0[n] = *(const short8*)&Bb[row * 64 + ((l4 ^ (l15 & 7)) * 8)];
    }
    __builtin_amdgcn_sched_barrier(0);   // pin: h0 reads issue before h1 reads
    // h1 fragment reads (stay in flight during MFMA h0)
#pragma unroll
    for (int m = 0; m < MFRAG; ++m) {
      int row = mrow0 + m * 16 + l15;
      afr1[m] = *(const short8*)&Ab[row * 64 + (((4 + l4) ^ (l15 & 7)) * 8)];
    }
#pragma unroll
    for (int n = 0; n < NFRAG; ++n) {
      int row = ncol0 + n * 16 + l15;
      bfr1[n] = *(const short8*)&Bb[row * 64 + (((4 + l4) ^ (l15 & 7)) * 8)];
    }
    __builtin_amdgcn_sched_barrier(0);
    lgkmwait<MFRAG + NFRAG>();           // h0 landed; h1 still flying
    __builtin_amdgcn_sched_barrier(0);
    __builtin_amdgcn_s_setprio(1);
#pragma unroll
    for (int m = 0; m < MFRAG; ++m)
#pragma unroll
      for (int n = 0; n < NFRAG; ++n)
        acc[m][n] = __builtin_amdgcn_mfma_f32_16x16x32_bf16(afr0[m], bfr0[n], acc[m][n], 0, 0, 0);
    __builtin_amdgcn_s_setprio(0);
    lgkmwait<0>();                       // h1 landed
    __builtin_amdgcn_sched_barrier(0);
    __builtin_amdgcn_s_setprio(1);
#pragma unroll
    for (int m = 0; m < MFRAG; ++m)
#pragma unroll
      for (int n = 0; n < NFRAG; ++n)
        acc[m][n] = __builtin_amdgcn_mfma_f32_16x16x32_bf16(afr1[m], bfr1[n], acc[m][n], 0, 0, 0);
    __builtin_amdgcn_s_setprio(0);
    __builtin_amdgcn_sched_barrier(0);
  }

#pragma unroll
  for (int m = 0; m < MFRAG; ++m)
#pragma unroll
    for (int n = 0; n < NFRAG; ++n)
#pragma unroll
      for (int j = 0; j < 4; ++j) {
        int r = row0 + mrow0 + m * 16 + l4 * 4 + j;
        int cc = col0 + ncol0 + n * 16 + l15;
        if constexpr (BF16_OUT)
          ((unsigned short*)Cout)[(size_t)r * N + cc] = f2bf(acc[m][n][j]);
        else
          ((float*)Cout)[(size_t)r * N + cc] = acc[m][n][j];
      }
}

// ---------------- RoPE (in-place on fused QKV [2048][6144]) ----------------
__global__ __launch_bounds__(256) void rope_k(unsigned short* __restrict__ QKV) {
  int idx = blockIdx.x * blockDim.x + threadIdx.x;
  if (idx >= 2048 * 40 * 64) return;
  int j = idx & 63;
  int rest = idx >> 6;
  int slot = rest % 40;
  int s = rest / 40;
  int doff = (slot < 32) ? slot * 128 : 4096 + (slot - 32) * 128;
  unsigned short* p = QKV + (size_t)s * 6144 + doff;
  float inv = exp2f((float)j * -0.20762050593046015f);
  float ang = (float)s * inv;
  float sn, cs;
  sincosf(ang, &sn, &cs);
  float x1 = bf2f(p[j]), x2 = bf2f(p[j + 64]);
  p[j]      = f2bf(x1 * cs - x2 * sn);
  p[j + 64] = f2bf(x2 * cs + x1 * sn);
}

// ---------------- causal GQA flash attention, KV-SPLIT partials (round-16 verbatim) ----------------
__global__ __launch_bounds__(512, 4) void attn_part(
    const unsigned short* __restrict__ QKV,  // [2048][6144]
    unsigned short* __restrict__ Opart,      // [2][2048][4096]
    float* __restrict__ ML) {                // [2][2048][32][2]
  __shared__ unsigned short Ks[2][64 * 128];
  __shared__ unsigned short Vs[2][64 * 128];

  const int tid = threadIdx.x;
  const int wave = tid >> 6, lane = tid & 63;
  const int l15 = lane & 15, l4 = lane >> 4;

  const int bid = blockIdx.x;
  const int qt = 15 - (bid >> 6);
  const int rest = bid & 63;
  const int h = rest >> 1;
  const int half = rest & 1;
  const int hkv = h >> 2;
  const int q0 = qt * 128;
  const int qrow = q0 + wave * 16 + l15;
  const float C2 = 0.12751744219938793f;  // log2(e)/sqrt(128)

  const unsigned short* Qp = QKV + h * 128;
  const unsigned short* Kp = QKV + 4096 + hkv * 128;
  const unsigned short* Vp = QKV + 5120 + hkv * 128;

  const int vpr = tid >> 4;
  const int vd8 = tid & 15;
  const int vg8 = vpr >> 2, vjj = 2 * (vpr & 3);
  const int vn = vd8 >> 1, vch = (vd8 & 1) * 8;

  short8 qf[4];
#pragma unroll
  for (int kc = 0; kc < 4; ++kc)
    qf[kc] = *(const short8*)(Qp + (size_t)qrow * 6144 + kc * 32 + l4 * 8);

  f32x4 zv = {0.f, 0.f, 0.f, 0.f};
  f32x4 oacc[8];
#pragma unroll
  for (int n = 0; n < 8; ++n) oacc[n] = zv;
  float mrow = -3.0e38f, lrow = 0.f;

  auto stageK = [&](int kvn, int b) {
#pragma unroll
    for (int i = 0; i < 2; ++i) {
      int c = wave * 2 + i;
      int row = c * 4 + l4;
      int colel = (l15 * 8) ^ ((row & 7) << 3);
      gload_lds16(Kp + (size_t)(kvn + row) * 6144 + colel, &Ks[b][c * 512]);
    }
  };
  auto loadV = [&](int kvn, short8& va, short8& vb) {
    va = *(const short8*)(Vp + (size_t)(kvn + 2 * vpr) * 6144 + vd8 * 8);
    vb = *(const short8*)(Vp + (size_t)(kvn + 2 * vpr + 1) * 6144 + vd8 * 8);
  };
  auto writeV = [&](int b, const short8& va, const short8& vb) {
#pragma unroll
    for (int i = 0; i < 8; ++i) {
      int c = vch + i;
      unsigned int pack = (unsigned int)(unsigned short)va[i] |
                          ((unsigned int)(unsigned short)vb[i] << 16);
      *(unsigned int*)&Vs[b][vg8 * 1024 + vn * 128 + ((c ^ vn) & 15) * 8 + vjj] = pack;
    }
  };

  const int t0 = half * (qt + 1);
  const int t1 = t0 + (qt + 1);

  {
    short8 va, vb;
    stageK(t0 * 64, t0 & 1);
    loadV(t0 * 64, va, vb);
    writeV(t0 & 1, va, vb);
  }
  __syncthreads();

  for (int t = t0; t < t1; ++t) {
    const int cur = t & 1, nxt = cur ^ 1;
    const int kv0 = t * 64;
    const bool has_next = (t + 1 < t1);
    short8 va, vb;
    if (has_next) {
      stageK(kv0 + 64, nxt);
      loadV(kv0 + 64, va, vb);
    }

    f32x4 sacc[4];
#pragma unroll
    for (int cb = 0; cb < 4; ++cb) sacc[cb] = zv;
    __builtin_amdgcn_s_setprio(1);
#pragma unroll
    for (int cb = 0; cb < 4; ++cb) {
      int row = cb * 16 + l15;
      int sw = (row & 7) << 3;
#pragma unroll
      for (int kc = 0; kc < 4; ++kc) {
        short8 kf = *(const short8*)&Ks[cur][row * 128 + ((kc * 32 + l4 * 8) ^ sw)];
        sacc[cb] = __builtin_amdgcn_mfma_f32_16x16x32_bf16(kf, qf[kc], sacc[cb], 0, 0, 0);
      }
    }
    __builtin_amdgcn_s_setprio(0);

    if (kv0 + 63 > q0 + wave * 16) {
#pragma unroll
      for (int cb = 0; cb < 4; ++cb)
#pragma unroll
        for (int j = 0; j < 4; ++j) {
          int kvpos = kv0 + cb * 16 + l4 * 4 + j;
          if (kvpos > qrow) sacc[cb][j] = -3.0e38f;
        }
    }

    float pm = sacc[0][0];
#pragma unroll
    for (int cb = 0; cb < 4; ++cb)
#pragma unroll
      for (int j = 0; j < 4; ++j) pm = fmaxf(pm, sacc[cb][j]);
    pm = fmaxf(pm, __shfl_xor(pm, 16, 64));
    pm = fmaxf(pm, __shfl_xor(pm, 32, 64));

    if (__any(pm > mrow + 64.0f)) {
      float mn = fmaxf(mrow, pm);
      float rs = exp2f((mrow - mn) * C2);
      mrow = mn;
      lrow *= rs;
      float rs0 = __shfl(rs, 4 * l4 + 0, 64);
      float rs1 = __shfl(rs, 4 * l4 + 1, 64);
      float rs2 = __shfl(rs, 4 * l4 + 2, 64);
      float rs3 = __shfl(rs, 4 * l4 + 3, 64);
#pragma unroll
      for (int n = 0; n < 8; ++n) {
        oacc[n][0] *= rs0; oacc[n][1] *= rs1;
        oacc[n][2] *= rs2; oacc[n][3] *= rs3;
      }
    }

    unsigned int pack[8];
    float psum = 0.f;
#pragma unroll
    for (int cb = 0; cb < 4; ++cb) {
      float p0 = exp2f((sacc[cb][0] - mrow) * C2);
      float p1 = exp2f((sacc[cb][1] - mrow) * C2);
      float p2 = exp2f((sacc[cb][2] - mrow) * C2);
      float p3 = exp2f((sacc[cb][3] - mrow) * C2);
      psum += (p0 + p1) + (p2 + p3);
      pack[cb * 2 + 0] = cvt_pk_bf16(p0, p1);
      pack[cb * 2 + 1] = cvt_pk_bf16(p2, p3);
    }
    lrow += psum;

#pragma unroll
    for (int ks = 0; ks < 2; ++ks) {
      u32x4 pw;
#pragma unroll
      for (int w = 0; w < 4; ++w) {
        int sl = l15 + 16 * ((2 * l4 + (w >> 1)) & 3);
        int v0 = __shfl((int)pack[4 * ks + (w & 1)], sl, 64);
        int v1 = __shfl((int)pack[4 * ks + 2 + (w & 1)], sl, 64);
        pw[w] = (lane < 32) ? (unsigned int)v0 : (unsigned int)v1;
      }
      short8 pf = __builtin_bit_cast(short8, pw);
      __builtin_amdgcn_s_setprio(1);
#pragma unroll
      for (int n = 0; n < 8; ++n) {
        short8 vf = *(const short8*)&Vs[cur][(ks * 4 + l4) * 1024 + n * 128 + ((l15 ^ n) & 15) * 8];
        oacc[n] = __builtin_amdgcn_mfma_f32_16x16x32_bf16(pf, vf, oacc[n], 0, 0, 0);
      }
      __builtin_amdgcn_s_setprio(0);
    }

    if (has_next) writeV(nxt, va, vb);
    __syncthreads();
  }

  lrow += __shfl_xor(lrow, 16, 64);
  lrow += __shfl_xor(lrow, 32, 64);
  if (l4 == 0) {
    int r = q0 + wave * 16 + l15;
    *(float2*)&ML[((size_t)half * 2048 + r) * 64 + h * 2] = make_float2(mrow, lrow);
  }
  float linv = 1.0f / lrow;
  float li0 = __shfl(linv, 4 * l4 + 0, 64);
  float li1 = __shfl(linv, 4 * l4 + 1, 64);
  float li2 = __shfl(linv, 4 * l4 + 2, 64);
  float li3 = __shfl(linv, 4 * l4 + 3, 64);
  unsigned short* Oh = Opart + (size_t)half * 2048 * 4096;
#pragma unroll
  for (int n = 0; n < 8; ++n) {
    int r = q0 + wave * 16 + l4 * 4;
    size_t base = (size_t)r * 4096 + h * 128 + n * 16 + l15;
    Oh[base]          = f2bf_fast(oacc[n][0] * li0);
    Oh[base + 4096]   = f2bf_fast(oacc[n][1] * li1);
    Oh[base + 8192]   = f2bf_fast(oacc[n][2] * li2);
    Oh[base + 12288]  = f2bf_fast(oacc[n][3] * li3);
  }
}

// ---------------- merge the two KV-half partials ----------------
__global__ __launch_bounds__(256) void merge_k(
    const unsigned short* __restrict__ Opart, const float* __restrict__ ML,
    unsigned short* __restrict__ Ob) {
  int idx = blockIdx.x * 256 + threadIdx.x;
  int d8 = idx & 15;
  int rest = idx >> 4;
  int h = rest & 31;
  int r = rest >> 5;
  const float C2 = 0.12751744219938793f;
  float2 ml0 = *(const float2*)&ML[(size_t)r * 64 + h * 2];
  float2 ml1 = *(const float2*)&ML[((size_t)2048 + r) * 64 + h * 2];
  float m = fmaxf(ml0.x, ml1.x);
  float w0 = ml0.y * exp2f((ml0.x - m) * C2);
  float w1 = ml1.y * exp2f((ml1.x - m) * C2);
  float inv = 1.0f / (w0 + w1);
  w0 *= inv; w1 *= inv;
  size_t off = (size_t)r * 4096 + h * 128 + d8 * 8;
  short8 a = *(const short8*)(Opart + off);
  short8 b = *(const short8*)(Opart + (size_t)2048 * 4096 + off);
  short8 o;
#pragma unroll
  for (int i = 0; i < 8; ++i)
    o[i] = (short)f2bf_fast(w0 * bf2f((unsigned short)a[i]) + w1 * bf2f((unsigned short)b[i]));
  *(short8*)(Ob + off) = o;
}

extern "C" void kernel_launch(void* const* d_in, const int* in_sizes, int n_in,
                              void* d_out, int out_size, void* d_ws, size_t ws_size,
                              hipStream_t stream) {
  const float* hid = (const float*)d_in[0];
  const float* Wq  = (const float*)d_in[1];
  const float* Wk  = (const float*)d_in[2];
  const float* Wv  = (const float*)d_in[3];
  const float* Wo  = (const float*)d_in[4];

  char* ws = (char*)d_ws;
  size_t off = 0;
  unsigned short* hid_b = (unsigned short*)(ws + off); off += (size_t)2048 * 4096 * 2;
  unsigned short* Wq_b  = (unsigned short*)(ws + off); off += (size_t)4096 * 4096 * 2;
  unsigned short* Wk_b  = (unsigned short*)(ws + off); off += (size_t)1024 * 4096 * 2;
  unsigned short* Wv_b  = (unsigned short*)(ws + off); off += (size_t)1024 * 4096 * 2;
  unsigned short* Wo_b  = (unsigned short*)(ws + off); off += (size_t)4096 * 4096 * 2;
  unsigned short* QKV   = (unsigned short*)(ws + off); off += (size_t)2048 * 6144 * 2;
  unsigned short* Ob    = (unsigned short*)(ws + off); off += (size_t)2048 * 4096 * 2;
  (void)Wv_b;

  // Opart/ML alias Wq_b/Wk_b (dead after the QKV projection completes).
  unsigned short* Opart = Wq_b;
  float*          MLb   = (float*)Wk_b;

  cvt_all<<<4096, 256, 0, stream>>>(hid, Wq, Wk, Wv, Wo, hid_b);

  gemm_p2<128, 192, true><<<dim3(32, 16), 256, 0, stream>>>(hid_b, Wq_b, (void*)QKV, 2048, 6144, 4096);

  rope_k<<<20480, 256, 0, stream>>>(QKV);

  attn_part<<<1024, 512, 0, stream>>>(QKV, Opart, MLb);
  merge_k<<<4096, 256, 0, stream>>>(Opart, MLb, Ob);

  gemm_p2<128, 128, false><<<dim3(32, 16), 256, 0, stream>>>(Ob, Wo_b, d_out, 2048, 4096, 4096);
}